// Round 4
// baseline (496.714 us; speedup 1.0000x reference)
//
#include <hip/hip_runtime.h>

// ExpLeak: out[b,t,n] = alpha*out[b,t-1,n] + in[b,t,n], alpha = exp(-1/tau).
// B=16, T=1024, N=4096, fp32.
//
// R5 = R4 with the nontemporal-store compile fix (use clang ext_vector_type;
// HIP_vector_type<float,4>* is rejected by __builtin_nontemporal_store).
//
// R4 strategy recap. R2 proved the 1-GiB ws re-poison fill (~165 us) happens
// UNCONDITIONALLY every iteration -> using d_ws is free; the headline carries
// a fixed ~165+ us reset tax. Optimize the part we control:
//   K1 (k_partial_ws): per (b, 32-row section) zero-init scan end E -> ws
//       (8 MB partials). Fully contiguous streaming.
//   K2 (k_apply_ws): per (b, section): compute own carry in-block via a <=31
//       step weighted FMA walk over the E-vectors in ws (L2/L3-resident,
//       coalesced) -- no separate k_scan dispatch -- then redo the seeded
//       scan from input (L3-hit re-read) and write out with NONTEMPORAL
//       stores (output never re-read; don't evict input from L3).
// Fallback (ws too small): R2's proven in-place 3-kernel scheme.

constexpr int T = 1024;
constexpr int N = 4096;
constexpr int B = 16;
constexpr int N4 = N / 4;     // 1024 float4 per row
constexpr int TS = 32;        // rows per section
constexpr int SEC = T / TS;   // 32 sections

typedef float floatx4 __attribute__((ext_vector_type(4)));

__device__ __forceinline__ float4 fma4(float a, float4 s, float4 x) {
  float4 r;
  r.x = fmaf(a, s.x, x.x);
  r.y = fmaf(a, s.y, x.y);
  r.z = fmaf(a, s.z, x.z);
  r.w = fmaf(a, s.w, x.w);
  return r;
}

__device__ __forceinline__ void nt_store4(float4 v, float4* p) {
  floatx4 t;
  t.x = v.x; t.y = v.y; t.z = v.z; t.w = v.w;
  __builtin_nontemporal_store(t, reinterpret_cast<floatx4*>(p));
}

// ---------------- primary path: partials in ws, 2 dispatches ----------------

// K1: E = zero-init scan end over the section's TS rows -> ws slot (b,s).
__global__ __launch_bounds__(1024) void k_partial_ws(
    const float4* __restrict__ in4, const float* __restrict__ tau_mem,
    float4* __restrict__ part4) {
  const int b = blockIdx.x / SEC;
  const int s = blockIdx.x % SEC;
  const int n4 = threadIdx.x;  // full 16 KB row per block
  const float alpha = expf(-1.0f / tau_mem[0]);
  const size_t base = (size_t)(b * T + s * TS) * N4 + n4;
  float4 S = make_float4(0.f, 0.f, 0.f, 0.f);
#pragma unroll 8
  for (int j = 0; j < TS; ++j) {
    S = fma4(alpha, S, in4[base + (size_t)j * N4]);
  }
  part4[(size_t)(b * SEC + s) * N4 + n4] = S;
}

// K2: carry = weighted sum of E_{b,0..s-1} (computed in-block from ws),
// then seeded scan from input, nontemporal store to out.
__global__ __launch_bounds__(1024) void k_apply_ws(
    const float4* __restrict__ in4, const float* __restrict__ tau_mem,
    const float4* __restrict__ part4, float4* __restrict__ out4) {
  const int b = blockIdx.x / SEC;
  const int s = blockIdx.x % SEC;
  const int n4 = threadIdx.x;
  const float alpha = expf(-1.0f / tau_mem[0]);
  const float aTS = expf(-(float)TS / tau_mem[0]);  // alpha^TS

  // carry into section s: C = sum_{j<s} aTS^{s-1-j} * E_j  (serial FMA walk,
  // E-vectors are L2/L3-resident; coalesced across the 1024 threads)
  float4 C = make_float4(0.f, 0.f, 0.f, 0.f);
  const float4* ebase = part4 + (size_t)(b * SEC) * N4 + n4;
  for (int j = 0; j < s; ++j) {
    C = fma4(aTS, C, ebase[(size_t)j * N4]);
  }

  const size_t base = (size_t)(b * T + s * TS) * N4 + n4;
  float4 S = C;
#pragma unroll 4
  for (int j = 0; j < TS; ++j) {
    S = fma4(alpha, S, in4[base + (size_t)j * N4]);
    nt_store4(S, &out4[base + (size_t)j * N4]);
  }
}

// ---------------- fallback path: R2's proven in-place scheme ----------------

__global__ __launch_bounds__(1024) void k_partial_ip(
    const float4* __restrict__ in4, const float* __restrict__ tau_mem,
    float4* __restrict__ out4) {
  const int b = blockIdx.x / SEC;
  const int s = blockIdx.x % SEC;
  const int n4 = threadIdx.x;
  const float alpha = expf(-1.0f / tau_mem[0]);
  const size_t base = (size_t)(b * T + s * TS) * N4 + n4;
  float4 S = make_float4(0.f, 0.f, 0.f, 0.f);
#pragma unroll 8
  for (int j = 0; j < TS; ++j) {
    S = fma4(alpha, S, in4[base + (size_t)j * N4]);
  }
  out4[base] = S;
}

__global__ __launch_bounds__(256) void k_scan_ip(
    float4* __restrict__ out4, const float* __restrict__ tau_mem) {
  const int t = blockIdx.x * blockDim.x + threadIdx.x;
  if (t >= B * N4) return;
  const int b = t >> 10;
  const int n4 = t & (N4 - 1);
  const float aTS = expf(-(float)TS / tau_mem[0]);
  float4* col = out4 + (size_t)b * T * N4 + n4;
  float4 C = make_float4(0.f, 0.f, 0.f, 0.f);
  for (int s = 0; s < SEC; ++s) {
    const size_t off = (size_t)(s * TS) * N4;
    float4 e = col[off];
    col[off] = C;
    C = fma4(aTS, C, e);
  }
}

__global__ __launch_bounds__(1024) void k_apply_ip(
    const float4* __restrict__ in4, const float* __restrict__ tau_mem,
    float4* __restrict__ out4) {
  const int b = blockIdx.x / SEC;
  const int s = blockIdx.x % SEC;
  const int n4 = threadIdx.x;
  const float alpha = expf(-1.0f / tau_mem[0]);
  const size_t base = (size_t)(b * T + s * TS) * N4 + n4;
  float4 S = out4[base];
#pragma unroll 4
  for (int j = 0; j < TS; ++j) {
    S = fma4(alpha, S, in4[base + (size_t)j * N4]);
    out4[base + (size_t)j * N4] = S;
  }
}

extern "C" void kernel_launch(void* const* d_in, const int* in_sizes, int n_in,
                              void* d_out, int out_size, void* d_ws, size_t ws_size,
                              hipStream_t stream) {
  const float4* in4 = (const float4*)d_in[0];
  const float* tau = (const float*)d_in[1];
  float4* out4 = (float4*)d_out;

  const size_t need = (size_t)B * SEC * N * sizeof(float);  // 8 MB partials
  if (d_ws != nullptr && ws_size >= need) {
    float4* part4 = (float4*)d_ws;
    k_partial_ws<<<B * SEC, 1024, 0, stream>>>(in4, tau, part4);
    k_apply_ws<<<B * SEC, 1024, 0, stream>>>(in4, tau, part4, out4);
  } else {
    k_partial_ip<<<B * SEC, 1024, 0, stream>>>(in4, tau, out4);
    k_scan_ip<<<(B * N4) / 256, 256, 0, stream>>>(out4, tau);
    k_apply_ip<<<B * SEC, 1024, 0, stream>>>(in4, tau, out4);
  }
}